// Round 5
// baseline (499.613 us; speedup 1.0000x reference)
//
#include <hip/hip_runtime.h>

#define LAT 64
#define ELLC 64       // ELL row capacity (deg ~ Poisson(32); overflow -> rovf)

// fp8 (e4m3) y-state, per-layer scale s_k = SC0 * RSC^k (round-0 notes).
// x0 (dominant output term) bypasses fp8: qacc initialized from fp32 embeds.
// R4 post-mortem: prop is a balanced VMEM/DS/latency mix at ~36.5us; the
// dominant remaining cost was preprocessing (~106us) whose bin+build double
// pass paid 9.6M LDS/global atomics + a 32MB bbuf round trip. This version:
// DIRECT ELL build -- one global atomicAdd per directed record (3.2M on 100k
// addresses, low contention) + scattered 4B col writes into L2-resident colE.
#define SC0 64.0f
#define RSC 3.0f

typedef float f32x2 __attribute__((ext_vector_type(2)));

// ---------- phase 1: direct ELL build (single pass over edges) ----------
__global__ void __launch_bounds__(256)
ell_k(const int* __restrict__ eu, const int* __restrict__ ei,
      int* __restrict__ cnt, int* __restrict__ colE,
      int2* __restrict__ rovf, int* __restrict__ rovfc,
      int E, int U, int rovf_cap) {
    int tid = blockIdx.x * blockDim.x + threadIdx.x;
    int stride = gridDim.x * blockDim.x;
    for (int d = tid; d < E; d += stride) {
        int u = eu[d], c = ei[d] + U;
        int pos = atomicAdd(&cnt[u], 1);
        if (pos < ELLC) colE[(size_t)u * ELLC + pos] = c;
        else { int o = atomicAdd(rovfc, 1); if (o < rovf_cap) rovf[o] = make_int2(u, c); }
        pos = atomicAdd(&cnt[c], 1);
        if (pos < ELLC) colE[(size_t)c * ELLC + pos] = u;
        else { int o = atomicAdd(rovfc, 1); if (o < rovf_cap) rovf[o] = make_int2(c, u); }
    }
}

// ---------- phase 2: fused pad + dinv + fp8 y0 (one wave per row) ----------
// Pads unused colE slots with 0 (a valid row index): prop's transposed
// col-register preload reads all 64 slots unconditionally.
__global__ void __launch_bounds__(256)
y0_k(const int* __restrict__ cnt, int* __restrict__ colE, float* __restrict__ dinv,
     const float* __restrict__ ue, const float* __restrict__ ie,
     unsigned char* __restrict__ y0, int N, int U) {
    int r = blockIdx.x * (blockDim.x >> 6) + (threadIdx.x >> 6);
    int lane = threadIdx.x & 63;
    if (r >= N) return;
    int d = cnt[r];
    if (lane >= min(d, ELLC)) colE[(size_t)r * ELLC + lane] = 0;
    float dv = (d > 0) ? rsqrtf((float)d) : 0.0f;
    if (lane == 0) dinv[r] = dv;
    if (lane < 16) {
        const float* s = (r < U) ? (ue + (size_t)r * LAT) : (ie + (size_t)(r - U) * LAT);
        float4 f = ((const float4*)s)[lane];
        float sc = SC0 * dv;
        int p = __builtin_amdgcn_cvt_pk_fp8_f32(sc * f.x, sc * f.y, 0, false);
        p = __builtin_amdgcn_cvt_pk_fp8_f32(sc * f.z, sc * f.w, p, true);
        ((unsigned*)y0)[(size_t)r * 16 + lane] = (unsigned)p;
    }
}

// ---------- propagation core (unchanged from R4) ----------
// unpack one fp8 dword into 4 accumulator floats
__device__ __forceinline__ void acc_word(unsigned w, float* r) {
    f32x2 lo = __builtin_amdgcn_cvt_pk_f32_fp8((int)w, false);
    f32x2 hi = __builtin_amdgcn_cvt_pk_f32_fp8((int)w, true);
    r[0] += lo[0]; r[1] += lo[1]; r[2] += hi[0]; r[3] += hi[1];
}

// Row waves: 4 nodes/wave, one per 16-lane group. Lane decomposition within
// group: q = (lane>>2)&3 = neighbor slot (4 in flight), s4 = lane&3 = 16B
// chunk (dims 16*s4..16*s4+15). Cols preloaded TRANSPOSED: lane gl holds
// cols {gl, gl+16, gl+32, gl+48} -> step s (neighbors 4s..4s+3) needs one
// shfl from lane 4*(s&3)+q, compile-time component s>>2.
// Waves [NW, NW+2B): query gather (first: qacc = e0 exact fp32; else += x_k).
__global__ void __launch_bounds__(256, 4)
prop_h_k(const int* __restrict__ cnt, const int* __restrict__ colE,
         const float* __restrict__ dinv, const unsigned char* __restrict__ yin,
         unsigned char* __restrict__ yout,
         const int* __restrict__ users, const int* __restrict__ items,
         float* __restrict__ qacc,
         const float* __restrict__ ue, const float* __restrict__ ie,
         const int2* __restrict__ rovf, const int* __restrict__ rovfc,
         int rovf_cap, int B, int U, int first, int N, float inv_sin) {
    int wave = blockIdx.x * (blockDim.x >> 6) + (threadIdx.x >> 6);
    int lane = threadIdx.x & 63;
    int NW = (N + 3) >> 2;
    if (wave >= NW) {
        int qw = wave - NW;
        if (qw >= 2 * B) return;
        int node = (qw < B) ? users[qw] : (items[qw - B] + U);
        if (first) {
            float v = (node < U) ? ue[(size_t)node * LAT + lane]
                                 : ie[(size_t)(node - U) * LAT + lane];
            qacc[qw * LAT + lane] = v;
        } else {
            float di = dinv[node];
            unsigned bb = yin[(size_t)node * LAT + lane];      // one 64B line/wave
            f32x2 yv = __builtin_amdgcn_cvt_pk_f32_fp8((int)bb, false);
            qacc[qw * LAT + lane] += (di > 0.0f) ? yv[0] * inv_sin / di : 0.0f;
        }
        return;
    }
    int grp  = lane >> 4;          // group 0..3 -> node
    int gbase = lane & 48;         // grp*16
    int q  = (lane >> 2) & 3;      // neighbor slot within step
    int s4 = lane & 3;             // 16B chunk: dims 16*s4..16*s4+15
    int node = (wave << 2) + grp;
    int nadr = min(node, N - 1);   // clamped address for tail groups
    int len = (node < N) ? min(cnt[nadr], ELLC) : 0;
    const int* cp = colE + (size_t)nadr * ELLC;
    // transposed col registers: lane gl holds cols gl+16c (4 coalesced loads)
    int gl = lane & 15;
    int ca0 = cp[gl], ca1 = cp[16 + gl], ca2 = cp[32 + gl], ca3 = cp[48 + gl];
    // wave-uniform step bound (max len over the 4 groups)
    int wmax = len;
    wmax = max(wmax, __shfl_xor(wmax, 16));
    wmax = max(wmax, __shfl_xor(wmax, 32));
    wmax = __builtin_amdgcn_readfirstlane(wmax);
    const uint4* y16 = (const uint4*)yin;

    float r[16];
#pragma unroll
    for (int j = 0; j < 16; ++j) r[j] = 0.f;

#pragma unroll
    for (int c = 0; c < 4; ++c) {
        int cac = (c == 0) ? ca0 : (c == 1) ? ca1 : (c == 2) ? ca2 : ca3;
#pragma unroll
        for (int si = 0; si < 4; ++si) {
            int s = (c << 2) + si;
            if ((s << 2) < wmax) {                 // wave-uniform guard
                int col = __shfl(cac, gbase + (si << 2) + q);   // 1 shfl / 4 nbrs
                if ((s << 2) + q < len) {          // per-lane validity
                    uint4 v = y16[(size_t)col * 4 + s4];
                    acc_word(v.x, r + 0); acc_word(v.y, r + 4);
                    acc_word(v.z, r + 8); acc_word(v.w, r + 12);
                }
            }
        }
    }
    // inline overflow epilogue (rovf static across layers; expected empty):
    // q==0 lanes (s4 = 0..3) cover the full row; reduce sums it in.
    int novf = min(*rovfc, rovf_cap);
    for (int o = 0; o < novf; ++o) {
        int2 eo = rovf[o];
        if (eo.x == node && q == 0) {
            uint4 vv = y16[(size_t)eo.y * 4 + s4];
            acc_word(vv.x, r + 0); acc_word(vv.y, r + 4);
            acc_word(vv.z, r + 8); acc_word(vv.w, r + 12);
        }
    }
    // reduce-scatter across q (12 shfl): stage A xor4 (q bit0), keep 8 dims;
    // stage B xor8 (q bit1), keep 4. Lane ends with dims d0..d0+3 fully
    // summed, d0 = 16*s4 + 8*b2 + 4*b3.
    {
        bool hi = (lane & 4) != 0;
        float s8[8], k8[8];
#pragma unroll
        for (int i = 0; i < 8; ++i) { k8[i] = hi ? r[8 + i] : r[i]; s8[i] = hi ? r[i] : r[8 + i]; }
#pragma unroll
        for (int i = 0; i < 8; ++i) r[i] = k8[i] + __shfl_xor(s8[i], 4);
    }
    {
        bool hi = (lane & 8) != 0;
        float s4a[4], k4a[4];
#pragma unroll
        for (int i = 0; i < 4; ++i) { k4a[i] = hi ? r[4 + i] : r[i]; s4a[i] = hi ? r[i] : r[4 + i]; }
#pragma unroll
        for (int i = 0; i < 4; ++i) r[i] = k4a[i] + __shfl_xor(s4a[i], 8);
    }
    // zero-shuffle pack + store: lane packs its 4 dims into 1 dword; 64 lanes
    // store 4 nodes x 64B coalesced.
    float dv = dinv[nadr];
    float f = dv * dv * RSC;               // fold out/in scale ratio into dinv^2
    int pk = __builtin_amdgcn_cvt_pk_fp8_f32(f * r[0], f * r[1], 0, false);
    pk = __builtin_amdgcn_cvt_pk_fp8_f32(f * r[2], f * r[3], pk, true);
    if (node < N) {
        int b2 = (lane >> 2) & 1, b3 = (lane >> 3) & 1;
        ((unsigned*)yout)[(size_t)node * 16 + (s4 << 2) + (b2 << 1) + b3] = (unsigned)pk;
    }
}

// final: qacc += x4 at queried nodes, then gamma = dot/25 (fused last qgather)
__global__ void final_k(const float* __restrict__ qacc, const unsigned char* __restrict__ y4,
                        const float* __restrict__ dinv,
                        const int* __restrict__ users, const int* __restrict__ items,
                        float* __restrict__ out, int B, int U, float inv_s4) {
    int wave = blockIdx.x * (blockDim.x >> 6) + (threadIdx.x >> 6);
    int lane = threadIdx.x & 63;
    if (wave >= B) return;
    int un = users[wave];
    int in = items[wave] + U;
    float du = dinv[un], di = dinv[in];
    unsigned bu = y4[(size_t)un * LAT + lane];
    unsigned bi = y4[(size_t)in * LAT + lane];
    f32x2 xuv = __builtin_amdgcn_cvt_pk_f32_fp8((int)bu, false);
    f32x2 xiv = __builtin_amdgcn_cvt_pk_f32_fp8((int)bi, false);
    float au = qacc[wave * LAT + lane]       + ((du > 0.f) ? xuv[0] * inv_s4 / du : 0.f);
    float ai = qacc[(wave + B) * LAT + lane] + ((di > 0.f) ? xiv[0] * inv_s4 / di : 0.f);
    float p = au * ai;
#pragma unroll
    for (int off = 32; off > 0; off >>= 1) p += __shfl_down(p, off);
    if (lane == 0) out[wave] = p * (1.0f / 25.0f);
}

extern "C" void kernel_launch(void* const* d_in, const int* in_sizes, int n_in,
                              void* d_out, int out_size, void* d_ws, size_t ws_size,
                              hipStream_t stream) {
    const float* ue = (const float*)d_in[0];
    const float* ie = (const float*)d_in[1];
    const int* edge = (const int*)d_in[2];
    const int* users = (const int*)d_in[3];
    const int* items = (const int*)d_in[4];

    const int U = in_sizes[0] / LAT;
    const int I = in_sizes[1] / LAT;
    const int N = U + I;
    const int E = in_sizes[2] / 2;
    const int B = in_sizes[3];
    const int* eu = edge;
    const int* ei = edge + E;

    char* ws = (char*)d_ws;
    size_t off = 0;
    auto alloc = [&](size_t bytes) -> void* {
        void* p = ws + off;
        off += (bytes + 255) & ~(size_t)255;
        return p;
    };
    // cnt + rovfc adjacent -> single memset covers both
    size_t zoff = off;
    int*           cnt   = (int*)alloc((size_t)4 * N);
    int*           rovfc = (int*)alloc(256);
    size_t zbytes = off - zoff;
    float*         dinv = (float*)alloc((size_t)4 * N);
    int*           colE = (int*)alloc((size_t)4 * N * ELLC);     // 25.6 MB
    unsigned char* yA   = (unsigned char*)alloc((size_t)N * LAT); // 6.4 MB fp8
    unsigned char* yB   = (unsigned char*)alloc((size_t)N * LAT);
    float*         qacc = (float*)alloc((size_t)4 * 2 * B * LAT);
    size_t remain = (ws_size > off + 256) ? (ws_size - off - 256) : 0;
    int rovf_cap = (int)min((size_t)131072, remain / sizeof(int2));
    int2* rovf = (int2*)alloc((size_t)rovf_cap * sizeof(int2));

    hipError_t _e = hipMemsetAsync(cnt, 0, zbytes, stream); (void)_e;

    const int tb = 256;

    // direct ELL: 2048 blocks x 256 thr grid-stride (524k lanes, ~3 edges each)
    ell_k<<<2048, tb, 0, stream>>>(eu, ei, cnt, colE, rovf, rovfc, E, U, rovf_cap);
    y0_k<<<(N + 3) / 4, tb, 0, stream>>>(cnt, colE, dinv, ue, ie, yA, N, U);

    const int wpb = tb / 64;
    const int NW = (N + 3) >> 2;               // 4 nodes per row-wave
    int pgrid = (NW + 2 * B + wpb - 1) / wpb;  // row waves + fused query waves

    unsigned char* yin = yA;
    unsigned char* yout = yB;
    float s_in = SC0;
    for (int layer = 0; layer < 4; ++layer) {
        prop_h_k<<<pgrid, tb, 0, stream>>>(cnt, colE, dinv, yin, yout,
                                           users, items, qacc, ue, ie, rovf, rovfc,
                                           rovf_cap, B, U, layer == 0 ? 1 : 0, N,
                                           1.0f / s_in);
        s_in *= RSC;
        unsigned char* tmp = yin; yin = yout; yout = tmp;
    }

    final_k<<<(B + wpb - 1) / wpb, tb, 0, stream>>>(qacc, yin, dinv, users, items,
                                                    (float*)d_out, B, U, 1.0f / s_in);
}

// Round 6
// 241.545 us; speedup vs baseline: 2.0684x; 2.0684x over previous
//
#include <hip/hip_runtime.h>

#define LAT 64
#define ELLC 64       // ELL row capacity (deg ~ Poisson(32); overflow handled)
#define RB 128        // rows per bucket (128x64x4B = 32KB LDS ELL stage)
#define RBSH 7
#define MAXBUK 1024   // static LDS sizing; nbuk = ceil(N/128) = 782 for N=100k
#define RPT 8         // undirected edges cached per thread (256 x 1024 x 8 >= E)

// fp8 (e4m3) y-state, per-layer scale s_k = SC0 * RSC^k (round-0 notes).
// x0 (dominant output term) bypasses fp8: qacc initialized from fp32 embeds.
// R5 post-mortem: direct global-atomic ELL build = 307us (WRITE_SIZE 192MB:
// scattered 4B writes -> partial-line writebacks; dependent atomic chains at
// ~900cy). Binned design justified. This round: build_k stages the bucket's
// ELL table in LDS (zero-init = free pad, LDS atomics, coalesced uint4
// writeout) instead of 3.2M uncoalesced 4B global writes.
#define SC0 64.0f
#define RSC 3.0f

typedef float f32x2 __attribute__((ext_vector_type(2)));

// ---------- phase 1: bin directed edges by row-bucket (single edge read) -----
// Packed word: (r & 127) << 17 | c   (needs N <= 131072).
__global__ void __launch_bounds__(1024)
bin_k(const int* __restrict__ eu, const int* __restrict__ ei,
      int* __restrict__ gcur, unsigned int* __restrict__ bbuf,
      int2* __restrict__ ovf, int* __restrict__ ovfc,
      int E, int U, int nbuk, int cap, int ovf_cap) {
    __shared__ int lcnt[MAXBUK];
    __shared__ int lbase[MAXBUK];
    for (int i = threadIdx.x; i < nbuk; i += blockDim.x) lcnt[i] = 0;
    __syncthreads();
    int tid = blockIdx.x * blockDim.x + threadIdx.x;
    int stride = gridDim.x * blockDim.x;
    int ru[RPT], rc[RPT];
    int ne = 0;
#pragma unroll
    for (int k = 0; k < RPT; ++k) {
        int d = tid + k * stride;
        if (d < E) {
            int u = eu[d], c = ei[d] + U;
            ru[k] = u; rc[k] = c; ne = k + 1;
            atomicAdd(&lcnt[u >> RBSH], 1);   // user-side row
            atomicAdd(&lcnt[c >> RBSH], 1);   // item-side row
        }
    }
    __syncthreads();
    for (int b = threadIdx.x; b < nbuk; b += blockDim.x)
        lbase[b] = atomicAdd(&gcur[b], lcnt[b]);      // global reservation
    __syncthreads();
#pragma unroll
    for (int k = 0; k < RPT; ++k) {
        if (k < ne) {
            int u = ru[k], c = rc[k];
            int b = u >> RBSH;
            int pos = atomicAdd(&lbase[b], 1);
            if (pos < cap)
                bbuf[(size_t)b * cap + pos] = ((unsigned)(u & (RB - 1)) << 17) | (unsigned)c;
            else { int o = atomicAdd(ovfc, 1); if (o < ovf_cap) ovf[o] = make_int2(u, c); }
            b = c >> RBSH;
            pos = atomicAdd(&lbase[b], 1);
            if (pos < cap)
                bbuf[(size_t)b * cap + pos] = ((unsigned)(c & (RB - 1)) << 17) | (unsigned)u;
            else { int o = atomicAdd(ovfc, 1); if (o < ovf_cap) ovf[o] = make_int2(c, u); }
        }
    }
}

// ---------- phase 2: per-bucket LDS-staged ELL + dinv + fused y0 (fp8) ------
// ELL table for the 128-row bucket lives in LDS (32KB): records placed via
// LDS atomic + ds_write (zero-init supplies the pad), then streamed out as
// coalesced uint4 -- no uncoalesced global writes.
__global__ void __launch_bounds__(1024)
build_k(const unsigned int* __restrict__ bbuf, const int* __restrict__ gcur,
        int* __restrict__ cnt, int* __restrict__ colE, float* __restrict__ dinv,
        const float* __restrict__ ue, const float* __restrict__ ie,
        unsigned char* __restrict__ y0,
        int2* __restrict__ rovf, int* __restrict__ rovfc,
        int N, int U, int cap, int rovf_cap) {
    __shared__ int lcnt[RB];
    __shared__ float ldv[RB];
    __shared__ int ell[RB * ELLC];   // 32KB
    int b = blockIdx.x;
    for (int i = threadIdx.x; i < RB; i += blockDim.x) lcnt[i] = 0;
    for (int i = threadIdx.x; i < RB * ELLC; i += blockDim.x) ell[i] = 0;
    __syncthreads();
    int nb = min(gcur[b], cap);
    const unsigned int* src = bbuf + (size_t)b * cap;
    for (int e = threadIdx.x; e < nb; e += blockDim.x) {
        unsigned w = src[e];
        int r7 = (int)(w >> 17);
        int c = (int)(w & 0x1FFFF);
        int pos = atomicAdd(&lcnt[r7], 1);
        if (pos < ELLC) ell[(r7 << 6) + pos] = c;
        else {
            int o = atomicAdd(rovfc, 1);
            if (o < rovf_cap) rovf[o] = make_int2((b << RBSH) + r7, c);
        }
    }
    __syncthreads();
    for (int i = threadIdx.x; i < RB; i += blockDim.x) {
        int r = (b << RBSH) + i;
        if (r < N) {
            int d = lcnt[i];
            cnt[r] = d;
            float dv = (d > 0) ? rsqrtf((float)d) : 0.0f;
            dinv[r] = dv;            // spill rows fixed in fix_k
            ldv[i] = dv;
        }
    }
    __syncthreads();
    int r0 = b << RBSH;
    int rows = min(RB, N - r0);
    // fused y0 = fp8(SC0 * dinv * e0) for this bucket's rows (coalesced uint)
    for (int w = threadIdx.x; w < rows * 16; w += blockDim.x) {
        int i = w >> 4, j = w & 15;         // word j covers dims 4j..4j+3
        int r = r0 + i;
        const float* s = (r < U) ? (ue + (size_t)r * LAT) : (ie + (size_t)(r - U) * LAT);
        float4 f = ((const float4*)s)[j];
        float sc = SC0 * ldv[i];
        int p = __builtin_amdgcn_cvt_pk_fp8_f32(sc * f.x, sc * f.y, 0, false);
        p = __builtin_amdgcn_cvt_pk_fp8_f32(sc * f.z, sc * f.w, p, true);
        ((unsigned*)y0)[(size_t)r * 16 + j] = (unsigned)p;
    }
    // coalesced ELL writeout: rows*64 ints = rows*16 uint4 (pad included)
    uint4* dst = (uint4*)(colE + (size_t)r0 * ELLC);
    const uint4* lsrc = (const uint4*)ell;
    for (int w = threadIdx.x; w < rows * 16; w += blockDim.x)
        dst[w] = lsrc[w];
}

// bin-phase spill fix-up + dinv + y0 repair (expected 0 entries). Single block;
// __syncthreads between phases so final cnt is seen.
__global__ void __launch_bounds__(1024)
fix_k(const int2* __restrict__ ovf, const int* __restrict__ ovfc,
      int* __restrict__ cnt, int* __restrict__ colE, float* __restrict__ dinv,
      const float* __restrict__ ue, const float* __restrict__ ie,
      unsigned char* __restrict__ y0,
      int2* __restrict__ rovf, int* __restrict__ rovfc,
      int ovf_cap, int rovf_cap, int U) {
    int n = min(*ovfc, ovf_cap);
    for (int i = threadIdx.x; i < n; i += blockDim.x) {
        int r = ovf[i].x, c = ovf[i].y;
        int pos = atomicAdd(&cnt[r], 1);
        if (pos < ELLC) colE[(size_t)r * ELLC + pos] = c;
        else { int o = atomicAdd(rovfc, 1); if (o < rovf_cap) rovf[o] = make_int2(r, c); }
    }
    __syncthreads();
    for (int i = threadIdx.x; i < n; i += blockDim.x) {
        int r = ovf[i].x;
        int d = cnt[r];
        dinv[r] = (d > 0) ? rsqrtf((float)d) : 0.0f;
    }
    __syncthreads();
    for (int w = threadIdx.x; w < n * 16; w += blockDim.x) {
        int o = w >> 4, j = w & 15;
        int r = ovf[o].x;
        const float* s = (r < U) ? (ue + (size_t)r * LAT) : (ie + (size_t)(r - U) * LAT);
        float4 f = ((const float4*)s)[j];
        float sc = SC0 * dinv[r];
        int p = __builtin_amdgcn_cvt_pk_fp8_f32(sc * f.x, sc * f.y, 0, false);
        p = __builtin_amdgcn_cvt_pk_fp8_f32(sc * f.z, sc * f.w, p, true);
        ((unsigned*)y0)[(size_t)r * 16 + j] = (unsigned)p;
    }
}

// ---------- propagation core (unchanged from R4) ----------
// unpack one fp8 dword into 4 accumulator floats
__device__ __forceinline__ void acc_word(unsigned w, float* r) {
    f32x2 lo = __builtin_amdgcn_cvt_pk_f32_fp8((int)w, false);
    f32x2 hi = __builtin_amdgcn_cvt_pk_f32_fp8((int)w, true);
    r[0] += lo[0]; r[1] += lo[1]; r[2] += hi[0]; r[3] += hi[1];
}

// Row waves: 4 nodes/wave, one per 16-lane group. Lane decomposition within
// group: q = (lane>>2)&3 = neighbor slot (4 in flight), s4 = lane&3 = 16B
// chunk (dims 16*s4..16*s4+15). Cols preloaded TRANSPOSED: lane gl holds
// cols {gl, gl+16, gl+32, gl+48} -> step s (neighbors 4s..4s+3) needs one
// shfl from lane 4*(s&3)+q, compile-time component s>>2.
// Waves [NW, NW+2B): query gather (first: qacc = e0 exact fp32; else += x_k).
__global__ void __launch_bounds__(256, 4)
prop_h_k(const int* __restrict__ cnt, const int* __restrict__ colE,
         const float* __restrict__ dinv, const unsigned char* __restrict__ yin,
         unsigned char* __restrict__ yout,
         const int* __restrict__ users, const int* __restrict__ items,
         float* __restrict__ qacc,
         const float* __restrict__ ue, const float* __restrict__ ie,
         const int2* __restrict__ rovf, const int* __restrict__ rovfc,
         int rovf_cap, int B, int U, int first, int N, float inv_sin) {
    int wave = blockIdx.x * (blockDim.x >> 6) + (threadIdx.x >> 6);
    int lane = threadIdx.x & 63;
    int NW = (N + 3) >> 2;
    if (wave >= NW) {
        int qw = wave - NW;
        if (qw >= 2 * B) return;
        int node = (qw < B) ? users[qw] : (items[qw - B] + U);
        if (first) {
            float v = (node < U) ? ue[(size_t)node * LAT + lane]
                                 : ie[(size_t)(node - U) * LAT + lane];
            qacc[qw * LAT + lane] = v;
        } else {
            float di = dinv[node];
            unsigned bb = yin[(size_t)node * LAT + lane];      // one 64B line/wave
            f32x2 yv = __builtin_amdgcn_cvt_pk_f32_fp8((int)bb, false);
            qacc[qw * LAT + lane] += (di > 0.0f) ? yv[0] * inv_sin / di : 0.0f;
        }
        return;
    }
    int grp  = lane >> 4;          // group 0..3 -> node
    int gbase = lane & 48;         // grp*16
    int q  = (lane >> 2) & 3;      // neighbor slot within step
    int s4 = lane & 3;             // 16B chunk: dims 16*s4..16*s4+15
    int node = (wave << 2) + grp;
    int nadr = min(node, N - 1);   // clamped address for tail groups
    int len = (node < N) ? min(cnt[nadr], ELLC) : 0;
    const int* cp = colE + (size_t)nadr * ELLC;
    // transposed col registers: lane gl holds cols gl+16c (4 coalesced loads)
    int gl = lane & 15;
    int ca0 = cp[gl], ca1 = cp[16 + gl], ca2 = cp[32 + gl], ca3 = cp[48 + gl];
    // wave-uniform step bound (max len over the 4 groups)
    int wmax = len;
    wmax = max(wmax, __shfl_xor(wmax, 16));
    wmax = max(wmax, __shfl_xor(wmax, 32));
    wmax = __builtin_amdgcn_readfirstlane(wmax);
    const uint4* y16 = (const uint4*)yin;

    float r[16];
#pragma unroll
    for (int j = 0; j < 16; ++j) r[j] = 0.f;

#pragma unroll
    for (int c = 0; c < 4; ++c) {
        int cac = (c == 0) ? ca0 : (c == 1) ? ca1 : (c == 2) ? ca2 : ca3;
#pragma unroll
        for (int si = 0; si < 4; ++si) {
            int s = (c << 2) + si;
            if ((s << 2) < wmax) {                 // wave-uniform guard
                int col = __shfl(cac, gbase + (si << 2) + q);   // 1 shfl / 4 nbrs
                if ((s << 2) + q < len) {          // per-lane validity
                    uint4 v = y16[(size_t)col * 4 + s4];
                    acc_word(v.x, r + 0); acc_word(v.y, r + 4);
                    acc_word(v.z, r + 8); acc_word(v.w, r + 12);
                }
            }
        }
    }
    // inline overflow epilogue (rovf static across layers; expected empty):
    // q==0 lanes (s4 = 0..3) cover the full row; reduce sums it in.
    int novf = min(*rovfc, rovf_cap);
    for (int o = 0; o < novf; ++o) {
        int2 eo = rovf[o];
        if (eo.x == node && q == 0) {
            uint4 vv = y16[(size_t)eo.y * 4 + s4];
            acc_word(vv.x, r + 0); acc_word(vv.y, r + 4);
            acc_word(vv.z, r + 8); acc_word(vv.w, r + 12);
        }
    }
    // reduce-scatter across q (12 shfl): stage A xor4 (q bit0), keep 8 dims;
    // stage B xor8 (q bit1), keep 4. Lane ends with dims d0..d0+3 fully
    // summed, d0 = 16*s4 + 8*b2 + 4*b3.
    {
        bool hi = (lane & 4) != 0;
        float s8[8], k8[8];
#pragma unroll
        for (int i = 0; i < 8; ++i) { k8[i] = hi ? r[8 + i] : r[i]; s8[i] = hi ? r[i] : r[8 + i]; }
#pragma unroll
        for (int i = 0; i < 8; ++i) r[i] = k8[i] + __shfl_xor(s8[i], 4);
    }
    {
        bool hi = (lane & 8) != 0;
        float s4a[4], k4a[4];
#pragma unroll
        for (int i = 0; i < 4; ++i) { k4a[i] = hi ? r[4 + i] : r[i]; s4a[i] = hi ? r[i] : r[4 + i]; }
#pragma unroll
        for (int i = 0; i < 4; ++i) r[i] = k4a[i] + __shfl_xor(s4a[i], 8);
    }
    // zero-shuffle pack + store: lane packs its 4 dims into 1 dword; 64 lanes
    // store 4 nodes x 64B coalesced.
    float dv = dinv[nadr];
    float f = dv * dv * RSC;               // fold out/in scale ratio into dinv^2
    int pk = __builtin_amdgcn_cvt_pk_fp8_f32(f * r[0], f * r[1], 0, false);
    pk = __builtin_amdgcn_cvt_pk_fp8_f32(f * r[2], f * r[3], pk, true);
    if (node < N) {
        int b2 = (lane >> 2) & 1, b3 = (lane >> 3) & 1;
        ((unsigned*)yout)[(size_t)node * 16 + (s4 << 2) + (b2 << 1) + b3] = (unsigned)pk;
    }
}

// final: qacc += x4 at queried nodes, then gamma = dot/25 (fused last qgather)
__global__ void final_k(const float* __restrict__ qacc, const unsigned char* __restrict__ y4,
                        const float* __restrict__ dinv,
                        const int* __restrict__ users, const int* __restrict__ items,
                        float* __restrict__ out, int B, int U, float inv_s4) {
    int wave = blockIdx.x * (blockDim.x >> 6) + (threadIdx.x >> 6);
    int lane = threadIdx.x & 63;
    if (wave >= B) return;
    int un = users[wave];
    int in = items[wave] + U;
    float du = dinv[un], di = dinv[in];
    unsigned bu = y4[(size_t)un * LAT + lane];
    unsigned bi = y4[(size_t)in * LAT + lane];
    f32x2 xuv = __builtin_amdgcn_cvt_pk_f32_fp8((int)bu, false);
    f32x2 xiv = __builtin_amdgcn_cvt_pk_f32_fp8((int)bi, false);
    float au = qacc[wave * LAT + lane]       + ((du > 0.f) ? xuv[0] * inv_s4 / du : 0.f);
    float ai = qacc[(wave + B) * LAT + lane] + ((di > 0.f) ? xiv[0] * inv_s4 / di : 0.f);
    float p = au * ai;
#pragma unroll
    for (int off = 32; off > 0; off >>= 1) p += __shfl_down(p, off);
    if (lane == 0) out[wave] = p * (1.0f / 25.0f);
}

extern "C" void kernel_launch(void* const* d_in, const int* in_sizes, int n_in,
                              void* d_out, int out_size, void* d_ws, size_t ws_size,
                              hipStream_t stream) {
    const float* ue = (const float*)d_in[0];
    const float* ie = (const float*)d_in[1];
    const int* edge = (const int*)d_in[2];
    const int* users = (const int*)d_in[3];
    const int* items = (const int*)d_in[4];

    const int U = in_sizes[0] / LAT;
    const int I = in_sizes[1] / LAT;
    const int N = U + I;
    const int E = in_sizes[2] / 2;
    const int B = in_sizes[3];
    const int* eu = edge;
    const int* ei = edge + E;

    const int nbuk = (N + RB - 1) / RB;                    // 782 for N=100k
    const int cap = ((2 * E / nbuk) * 5 / 4 + 255) & ~255; // ~25% slack

    char* ws = (char*)d_ws;
    size_t off = 0;
    auto alloc = [&](size_t bytes) -> void* {
        void* p = ws + off;
        off += (bytes + 255) & ~(size_t)255;
        return p;
    };
    int*           cnt  = (int*)alloc((size_t)4 * N);
    float*         dinv = (float*)alloc((size_t)4 * N);
    int*           colE = (int*)alloc((size_t)4 * N * ELLC);     // 25.6 MB
    unsigned char* yA   = (unsigned char*)alloc((size_t)N * LAT); // 6.4 MB fp8
    unsigned char* yB   = (unsigned char*)alloc((size_t)N * LAT);
    float*         qacc = (float*)alloc((size_t)4 * 2 * B * LAT);
    unsigned*      bbuf = (unsigned*)alloc((size_t)4 * nbuk * cap);  // ~17 MB
    // gcur and ovfc adjacent -> single memset covers both
    size_t zoff = off;
    int*      gcur = (int*)alloc((size_t)4 * nbuk);
    int*      ovfc = (int*)alloc(256);   // [0]=bin spill, [64]=row ovf
    size_t zbytes = off - zoff;
    size_t remain = (ws_size > off + 256) ? (ws_size - off - 256) : 0;
    int ovf_cap = (int)min((size_t)131072, remain / (2 * sizeof(int2)));
    int2* ovf  = (int2*)alloc((size_t)ovf_cap * sizeof(int2));
    int2* rovf = (int2*)alloc((size_t)ovf_cap * sizeof(int2));
    int* rovfc = ovfc + 64;

    hipError_t _e = hipMemsetAsync(gcur, 0, zbytes, stream); (void)_e;

    const int tb = 256;

    // 256 blocks x 1024 thr x RPT 8 = 2.1M >= E undirected edges
    bin_k<<<256, 1024, 0, stream>>>(eu, ei, gcur, bbuf, ovf, ovfc, E, U, nbuk, cap, ovf_cap);
    build_k<<<nbuk, 1024, 0, stream>>>(bbuf, gcur, cnt, colE, dinv, ue, ie, yA,
                                       rovf, rovfc, N, U, cap, ovf_cap);
    fix_k<<<1, 1024, 0, stream>>>(ovf, ovfc, cnt, colE, dinv, ue, ie, yA,
                                  rovf, rovfc, ovf_cap, ovf_cap, U);

    const int wpb = tb / 64;
    const int NW = (N + 3) >> 2;               // 4 nodes per row-wave
    int pgrid = (NW + 2 * B + wpb - 1) / wpb;  // row waves + fused query waves

    unsigned char* yin = yA;
    unsigned char* yout = yB;
    float s_in = SC0;
    for (int layer = 0; layer < 4; ++layer) {
        prop_h_k<<<pgrid, tb, 0, stream>>>(cnt, colE, dinv, yin, yout,
                                           users, items, qacc, ue, ie, rovf, rovfc,
                                           ovf_cap, B, U, layer == 0 ? 1 : 0, N,
                                           1.0f / s_in);
        s_in *= RSC;
        unsigned char* tmp = yin; yin = yout; yout = tmp;
    }

    final_k<<<(B + wpb - 1) / wpb, tb, 0, stream>>>(qacc, yin, dinv, users, items,
                                                    (float*)d_out, B, U, 1.0f / s_in);
}